// Round 1
// baseline (728.145 us; speedup 1.0000x reference)
//
#include <hip/hip_runtime.h>
#include <math.h>

// Problem constants (B, F, NP, DIM, H, DH) = (4, 16, 196, 512, 8, 64)
#define B_   4
#define F_   16
#define NP_  196
#define DIM_ 512
#define H_   8
#define DH_  64
#define NTOT 3137            // 1 + F*NP
#define BH_  32              // B*H
#define MROWS 12548          // B*NTOT

static const size_t QSZ = (size_t)BH_ * NTOT * DH_;  // 6,424,576 floats per q/k/v buffer

// ---------------------------------------------------------------------------
// Kernel 1: qkv GEMM.  C = x @ W_qkv  (M=12548, K=512, N=1536)
// Epilogue scatters into q/k/v workspace with layout [B*H][NTOT][DH],
// scaling q by DH^-0.5 = 0.125.
// ---------------------------------------------------------------------------
__global__ __launch_bounds__(256) void gemm_qkv_kernel(
    const float* __restrict__ x, const float* __restrict__ w, float* __restrict__ ws)
{
    __shared__ float As[16][128];   // As[k][m]  (transposed at staging)
    __shared__ float Bs[16][128];   // Bs[k][n]

    const int tid = threadIdx.x;
    const int tx = tid & 15, ty = tid >> 4;
    const int row0 = blockIdx.y * 128;
    const int col0 = blockIdx.x * 128;

    float acc[8][8];
    #pragma unroll
    for (int i = 0; i < 8; ++i)
        #pragma unroll
        for (int j = 0; j < 8; ++j) acc[i][j] = 0.f;

    for (int k0 = 0; k0 < DIM_; k0 += 16) {
        #pragma unroll
        for (int rep = 0; rep < 2; ++rep) {
            int f = tid + rep * 256;          // 0..511
            // A tile: 128 rows x 16 k -> 512 float4 (4 float4 per row)
            int m = f >> 2, k4 = f & 3;
            int grow = row0 + m;
            float4 val = make_float4(0.f, 0.f, 0.f, 0.f);
            if (grow < MROWS)
                val = *(const float4*)(x + (size_t)grow * DIM_ + k0 + k4 * 4);
            As[k4 * 4 + 0][m] = val.x;
            As[k4 * 4 + 1][m] = val.y;
            As[k4 * 4 + 2][m] = val.z;
            As[k4 * 4 + 3][m] = val.w;
            // B tile: 16 k x 128 cols -> 512 float4 (32 per k-row)
            int kb = f >> 5, c4 = f & 31;
            float4 bv = *(const float4*)(w + (size_t)(k0 + kb) * 1536 + col0 + c4 * 4);
            *(float4*)(&Bs[kb][c4 * 4]) = bv;
        }
        __syncthreads();
        #pragma unroll
        for (int kk = 0; kk < 16; ++kk) {
            float4 a0 = *(const float4*)(&As[kk][ty * 8]);
            float4 a1 = *(const float4*)(&As[kk][ty * 8 + 4]);
            float4 b0 = *(const float4*)(&Bs[kk][tx * 8]);
            float4 b1 = *(const float4*)(&Bs[kk][tx * 8 + 4]);
            float a[8] = {a0.x, a0.y, a0.z, a0.w, a1.x, a1.y, a1.z, a1.w};
            float b[8] = {b0.x, b0.y, b0.z, b0.w, b1.x, b1.y, b1.z, b1.w};
            #pragma unroll
            for (int i = 0; i < 8; ++i)
                #pragma unroll
                for (int j = 0; j < 8; ++j)
                    acc[i][j] = fmaf(a[i], b[j], acc[i][j]);
        }
        __syncthreads();
    }

    // Scatter epilogue: col j -> (t3 = j/512: q/k/v, h = (j%512)/64, d = j%64)
    const int col_base = col0 + tx * 8;     // multiple of 8; never crosses 64-col bdry
    const int t3 = col_base >> 9;
    const int rem = col_base & 511;
    const int h  = rem >> 6;
    const int d0 = rem & 63;
    const float scale = (t3 == 0) ? 0.125f : 1.0f;
    float* dst3 = ws + (size_t)t3 * QSZ;
    #pragma unroll
    for (int ii = 0; ii < 8; ++ii) {
        int i = row0 + ty * 8 + ii;
        if (i >= MROWS) break;
        int b = i / NTOT;
        int n = i - b * NTOT;
        float* dst = dst3 + ((size_t)(b * H_ + h) * NTOT + n) * DH_ + d0;
        *(float4*)(dst)     = make_float4(acc[ii][0] * scale, acc[ii][1] * scale,
                                          acc[ii][2] * scale, acc[ii][3] * scale);
        *(float4*)(dst + 4) = make_float4(acc[ii][4] * scale, acc[ii][5] * scale,
                                          acc[ii][6] * scale, acc[ii][7] * scale);
    }
}

// ---------------------------------------------------------------------------
// Kernel 2: fused attention.
//   blocks [0,512): local groups (bh, f): 196 q rows attend over cls + own 196 kv
//   blocks [512,544): cls rows: 1 q row attends over all 3137 kv
// Output written to attn workspace in [B][NTOT][H*DH] layout.
// ---------------------------------------------------------------------------
__global__ __launch_bounds__(256) void attn_kernel(
    const float* __restrict__ ws_q, const float* __restrict__ ws_k,
    const float* __restrict__ ws_v, float* __restrict__ attn)
{
    __shared__ float k_s[64 * 64];
    __shared__ float v_s[64 * 64];
    __shared__ float mrg[4 + 4 + 256];

    const int tid = threadIdx.x;
    const int g = blockIdx.x;

    if (g < 512) {
        // ---- local group attention ----
        const int bh = g >> 4;
        const int f  = g & 15;
        const int r  = min(tid, 195);            // threads 196..255 shadow row 195
        const int nq = 1 + f * NP_ + r;

        float4 q4[16];
        const float4* qrow = (const float4*)(ws_q + ((size_t)bh * NTOT + nq) * DH_);
        #pragma unroll
        for (int i = 0; i < 16; ++i) q4[i] = qrow[i];

        float m = -INFINITY, l = 0.f;
        float4 o[16];
        #pragma unroll
        for (int i = 0; i < 16; ++i) o[i] = make_float4(0.f, 0.f, 0.f, 0.f);

        for (int jt = 0; jt < 4; ++jt) {         // 197 kv rows in tiles of 64
            int cnt = min(64, 197 - jt * 64);
            __syncthreads();
            for (int idx = tid; idx < cnt * 16; idx += 256) {
                int j = idx >> 4, d4 = idx & 15;
                int jj = jt * 64 + j;
                int nkv = (jj == 0) ? 0 : (1 + f * NP_ + jj - 1);
                *(float4*)(&k_s[j * 64 + d4 * 4]) =
                    *(const float4*)(ws_k + ((size_t)bh * NTOT + nkv) * DH_ + d4 * 4);
                *(float4*)(&v_s[j * 64 + d4 * 4]) =
                    *(const float4*)(ws_v + ((size_t)bh * NTOT + nkv) * DH_ + d4 * 4);
            }
            __syncthreads();
            for (int j = 0; j < cnt; ++j) {
                const float4* kr = (const float4*)(k_s + j * 64);
                float s = 0.f;
                #pragma unroll
                for (int i = 0; i < 16; ++i) {
                    float4 kk = kr[i];
                    s = fmaf(q4[i].x, kk.x, s);
                    s = fmaf(q4[i].y, kk.y, s);
                    s = fmaf(q4[i].z, kk.z, s);
                    s = fmaf(q4[i].w, kk.w, s);
                }
                float mn = fmaxf(m, s);
                float p = __expf(s - mn);
                if (mn > m) {                    // rare (~log(197) times): rescale
                    float al = __expf(m - mn);
                    l *= al;
                    #pragma unroll
                    for (int i = 0; i < 16; ++i) {
                        o[i].x *= al; o[i].y *= al; o[i].z *= al; o[i].w *= al;
                    }
                }
                m = mn;
                l += p;
                const float4* vr = (const float4*)(v_s + j * 64);
                #pragma unroll
                for (int i = 0; i < 16; ++i) {
                    float4 vv = vr[i];
                    o[i].x = fmaf(p, vv.x, o[i].x);
                    o[i].y = fmaf(p, vv.y, o[i].y);
                    o[i].z = fmaf(p, vv.z, o[i].z);
                    o[i].w = fmaf(p, vv.w, o[i].w);
                }
            }
        }
        if (tid < 196) {
            const int b = bh >> 3, h = bh & 7;
            float inv = 1.f / l;
            float4* dst = (float4*)(attn + ((size_t)b * NTOT + nq) * DIM_ + h * DH_);
            #pragma unroll
            for (int i = 0; i < 16; ++i) {
                float4 t = o[i];
                dst[i] = make_float4(t.x * inv, t.y * inv, t.z * inv, t.w * inv);
            }
        }
    } else {
        // ---- cls attention: row 0 of (bh) over all 3137 kv ----
        const int bh = g - 512;
        const int lane = tid & 63, w = tid >> 6;
        const float qv = ws_q[(size_t)bh * NTOT * DH_ + lane];  // q row 0, element=lane

        float m = -INFINITY, l = 0.f, o = 0.f;
        for (int chunk = 0; chunk < NTOT; chunk += 64) {
            int cnt = min(64, NTOT - chunk);
            __syncthreads();
            for (int idx = tid; idx < cnt * 16; idx += 256) {
                int j = idx >> 4, d4 = idx & 15;
                int nkv = chunk + j;
                *(float4*)(&k_s[j * 64 + d4 * 4]) =
                    *(const float4*)(ws_k + ((size_t)bh * NTOT + nkv) * DH_ + d4 * 4);
                *(float4*)(&v_s[j * 64 + d4 * 4]) =
                    *(const float4*)(ws_v + ((size_t)bh * NTOT + nkv) * DH_ + d4 * 4);
            }
            __syncthreads();
            for (int j = w; j < cnt; j += 4) {   // waves split rows of the chunk
                float s = qv * k_s[j * 64 + lane];
                #pragma unroll
                for (int off = 32; off > 0; off >>= 1) s += __shfl_xor(s, off, 64);
                float mn = fmaxf(m, s);
                float p  = __expf(s - mn);
                float al = __expf(m - mn);
                l = l * al + p;
                o = o * al + p * v_s[j * 64 + lane];
                m = mn;
            }
        }
        __syncthreads();
        float* mb = mrg;  float* lb = mrg + 4;  float* ob = mrg + 8;
        if (lane == 0) { mb[w] = m; lb[w] = l; }   // m,l wave-uniform after shuffles
        ob[w * 64 + lane] = o;
        __syncthreads();
        if (w == 0) {
            float M = fmaxf(fmaxf(mb[0], mb[1]), fmaxf(mb[2], mb[3]));
            float L = 0.f, O = 0.f;
            #pragma unroll
            for (int i = 0; i < 4; ++i) {
                float al = __expf(mb[i] - M);
                L += lb[i] * al;
                O += ob[i * 64 + lane] * al;
            }
            const int b = bh >> 3, h = bh & 7;
            attn[((size_t)b * NTOT) * DIM_ + h * DH_ + lane] = O / L;
        }
    }
}

// ---------------------------------------------------------------------------
// Kernel 3: out GEMM.  out = attn @ W_out + b_out  (M=12548, K=512, N=512)
// ---------------------------------------------------------------------------
__global__ __launch_bounds__(256) void gemm_out_kernel(
    const float* __restrict__ a, const float* __restrict__ w,
    const float* __restrict__ bias, float* __restrict__ out)
{
    __shared__ float As[16][128];
    __shared__ float Bs[16][128];

    const int tid = threadIdx.x;
    const int tx = tid & 15, ty = tid >> 4;
    const int row0 = blockIdx.y * 128;
    const int col0 = blockIdx.x * 128;

    float acc[8][8];
    #pragma unroll
    for (int i = 0; i < 8; ++i)
        #pragma unroll
        for (int j = 0; j < 8; ++j) acc[i][j] = 0.f;

    for (int k0 = 0; k0 < DIM_; k0 += 16) {
        #pragma unroll
        for (int rep = 0; rep < 2; ++rep) {
            int f = tid + rep * 256;
            int m = f >> 2, k4 = f & 3;
            int grow = row0 + m;
            float4 val = make_float4(0.f, 0.f, 0.f, 0.f);
            if (grow < MROWS)
                val = *(const float4*)(a + (size_t)grow * DIM_ + k0 + k4 * 4);
            As[k4 * 4 + 0][m] = val.x;
            As[k4 * 4 + 1][m] = val.y;
            As[k4 * 4 + 2][m] = val.z;
            As[k4 * 4 + 3][m] = val.w;
            int kb = f >> 5, c4 = f & 31;
            float4 bv = *(const float4*)(w + (size_t)(k0 + kb) * DIM_ + col0 + c4 * 4);
            *(float4*)(&Bs[kb][c4 * 4]) = bv;
        }
        __syncthreads();
        #pragma unroll
        for (int kk = 0; kk < 16; ++kk) {
            float4 a0 = *(const float4*)(&As[kk][ty * 8]);
            float4 a1 = *(const float4*)(&As[kk][ty * 8 + 4]);
            float4 b0 = *(const float4*)(&Bs[kk][tx * 8]);
            float4 b1 = *(const float4*)(&Bs[kk][tx * 8 + 4]);
            float av[8] = {a0.x, a0.y, a0.z, a0.w, a1.x, a1.y, a1.z, a1.w};
            float bv[8] = {b0.x, b0.y, b0.z, b0.w, b1.x, b1.y, b1.z, b1.w};
            #pragma unroll
            for (int i = 0; i < 8; ++i)
                #pragma unroll
                for (int j = 0; j < 8; ++j)
                    acc[i][j] = fmaf(av[i], bv[j], acc[i][j]);
        }
        __syncthreads();
    }

    const int col_base = col0 + tx * 8;
    float bb[8];
    #pragma unroll
    for (int jj = 0; jj < 8; ++jj) bb[jj] = bias[col_base + jj];
    #pragma unroll
    for (int ii = 0; ii < 8; ++ii) {
        int i = row0 + ty * 8 + ii;
        if (i >= MROWS) break;
        float* dst = out + (size_t)i * DIM_ + col_base;
        *(float4*)(dst)     = make_float4(acc[ii][0] + bb[0], acc[ii][1] + bb[1],
                                          acc[ii][2] + bb[2], acc[ii][3] + bb[3]);
        *(float4*)(dst + 4) = make_float4(acc[ii][4] + bb[4], acc[ii][5] + bb[5],
                                          acc[ii][6] + bb[6], acc[ii][7] + bb[7]);
    }
}

// ---------------------------------------------------------------------------
extern "C" void kernel_launch(void* const* d_in, const int* in_sizes, int n_in,
                              void* d_out, int out_size, void* d_ws, size_t ws_size,
                              hipStream_t stream) {
    const float* x    = (const float*)d_in[0];
    const float* wqkv = (const float*)d_in[1];
    const float* wout = (const float*)d_in[2];
    const float* bout = (const float*)d_in[3];
    // d_in[4] is f=16, compiled in as a constant.

    float* ws   = (float*)d_ws;
    float* qws  = ws;               // [BH][NTOT][DH]
    float* kws  = ws + QSZ;
    float* vws  = ws + 2 * QSZ;
    float* attn = ws + 3 * QSZ;     // [B][NTOT][H*DH]
    float* outp = (float*)d_out;

    // qkv = x @ W_qkv, scatter to q/k/v (q pre-scaled by 0.125)
    gemm_qkv_kernel<<<dim3(12, 99), 256, 0, stream>>>(x, wqkv, ws);
    // fused local-group + cls attention
    attn_kernel<<<dim3(544), 256, 0, stream>>>(qws, kws, vws, attn);
    // out = attn @ W_out + b_out
    gemm_out_kernel<<<dim3(4, 99), 256, 0, stream>>>(attn, wout, bout, outp);
}

// Round 2
// 467.781 us; speedup vs baseline: 1.5566x; 1.5566x over previous
//
#include <hip/hip_runtime.h>
#include <math.h>

// (B, F, NP, DIM, H, DH) = (4, 16, 196, 512, 8, 64)
#define B_   4
#define F_   16
#define NP_  196
#define DIM_ 512
#define H_   8
#define DH_  64
#define NTOT 3137            // 1 + F*NP
#define BH_  32              // B*H
#define MROWS 12548          // B*NTOT
#define QSZ_ ((size_t)BH_ * NTOT * DH_)   // 6,424,576 elements per q/k/v buffer

typedef unsigned short u16;
typedef __attribute__((ext_vector_type(8))) short    bf16x8;
typedef __attribute__((ext_vector_type(8))) unsigned short u16x8;
typedef __attribute__((ext_vector_type(4))) unsigned short u16x4;
typedef __attribute__((ext_vector_type(4))) float    f32x4;

__device__ __forceinline__ u16 f2bf(float f) {
    unsigned int u = __float_as_uint(f);
    unsigned int r = (u + 0x7FFFu + ((u >> 16) & 1u)) >> 16;
    return (u16)r;
}

// ---------------------------------------------------------------------------
// convert x (fp32, MROWS x 512) -> bf16
// ---------------------------------------------------------------------------
__global__ __launch_bounds__(256) void convert_x_kernel(
    const float* __restrict__ x, u16* __restrict__ xbf)
{
    int idx = blockIdx.x * 256 + threadIdx.x;       // one float4 per thread
    float4 v = ((const float4*)x)[idx];
    u16x4 p = { f2bf(v.x), f2bf(v.y), f2bf(v.z), f2bf(v.w) };
    *(u16x4*)(&xbf[(size_t)idx * 4]) = p;
}

// ---------------------------------------------------------------------------
// transpose + bf16-convert: src (R x C fp32) -> dst (C x R bf16)
// ---------------------------------------------------------------------------
__global__ __launch_bounds__(256) void transpose_bf16_kernel(
    const float* __restrict__ src, u16* __restrict__ dst, int R, int C)
{
    __shared__ float t[32][33];
    const int tx = threadIdx.x & 31, ty = threadIdx.x >> 5;   // ty in 0..7
    const int c0 = blockIdx.x * 32, r0 = blockIdx.y * 32;
    #pragma unroll
    for (int i = 0; i < 4; ++i) {
        int r = ty + i * 8;
        t[r][tx] = src[(size_t)(r0 + r) * C + c0 + tx];
    }
    __syncthreads();
    #pragma unroll
    for (int i = 0; i < 4; ++i) {
        int cc = ty + i * 8;
        dst[(size_t)(c0 + cc) * R + r0 + tx] = f2bf(t[tx][cc]);
    }
}

// ---------------------------------------------------------------------------
// bf16 MFMA GEMM:  C = A(MROWS x 512) * BT^T   (BT is N x 512 bf16, K-contig)
// 128x128 block tile, BK=32, 4 waves in 2x2, each wave 64x64 via 4x4 mfma tiles.
// MODE 0: qkv epilogue (scatter to q/k/v ws [BH][NTOT][DH], q*0.125)
// MODE 1: out epilogue (+bias, fp32 row-major)
// ---------------------------------------------------------------------------
template<int MODE>
__global__ __launch_bounds__(256) void gemm_bf16_mfma(
    const u16* __restrict__ A, const u16* __restrict__ BT,
    float* __restrict__ C, const float* __restrict__ bias)
{
    __shared__ alignas(16) u16 Asm[8 * 512];   // subtile s: lane l holds A[s*16+(l&15)][k0+(l>>4)*8 + j]
    __shared__ alignas(16) u16 Bsm[8 * 512];

    const int tid  = threadIdx.x;
    const int wave = tid >> 6, lane = tid & 63;
    const int wr = wave >> 1, wc = wave & 1;
    const int lm = lane & 15, lq = lane >> 4;
    const int row0 = blockIdx.y * 128;
    const int col0 = blockIdx.x * 128;

    f32x4 acc[4][4];
    #pragma unroll
    for (int i = 0; i < 4; ++i)
        #pragma unroll
        for (int j = 0; j < 4; ++j) acc[i][j] = (f32x4){0.f, 0.f, 0.f, 0.f};

    for (int k0 = 0; k0 < 512; k0 += 32) {
        // stage: each wave fills 2 A-subtiles + 2 B-subtiles (64 lanes x 16B each)
        #pragma unroll
        for (int i = 0; i < 2; ++i) {
            int s = wave * 2 + i;
            int arow = row0 + s * 16 + lm;
            if (arow >= MROWS) arow = MROWS - 1;
            u16x8 av = *(const u16x8*)(A + (size_t)arow * 512 + k0 + lq * 8);
            *(u16x8*)(&Asm[s * 512 + lane * 8]) = av;
            int brow = col0 + s * 16 + lm;      // row of BT = output column
            u16x8 bv = *(const u16x8*)(BT + (size_t)brow * 512 + k0 + lq * 8);
            *(u16x8*)(&Bsm[s * 512 + lane * 8]) = bv;
        }
        __syncthreads();
        bf16x8 af[4], bf[4];
        #pragma unroll
        for (int mi = 0; mi < 4; ++mi)
            af[mi] = *(const bf16x8*)(&Asm[(wr * 4 + mi) * 512 + lane * 8]);
        #pragma unroll
        for (int ni = 0; ni < 4; ++ni)
            bf[ni] = *(const bf16x8*)(&Bsm[(wc * 4 + ni) * 512 + lane * 8]);
        #pragma unroll
        for (int mi = 0; mi < 4; ++mi)
            #pragma unroll
            for (int ni = 0; ni < 4; ++ni)
                acc[mi][ni] = __builtin_amdgcn_mfma_f32_16x16x32_bf16(
                    af[mi], bf[ni], acc[mi][ni], 0, 0, 0);
        __syncthreads();
    }

    // epilogue: lane l, reg r -> row = sub16 + lq*4 + r, col = sub16 + lm
    if (MODE == 0) {
        #pragma unroll
        for (int mi = 0; mi < 4; ++mi) {
            #pragma unroll
            for (int r = 0; r < 4; ++r) {
                int gr = row0 + wr * 64 + mi * 16 + lq * 4 + r;
                if (gr >= MROWS) continue;
                int b = gr / NTOT;              // const-div -> magic mul
                int n = gr - b * NTOT;
                #pragma unroll
                for (int ni = 0; ni < 4; ++ni) {
                    int gc = col0 + wc * 64 + ni * 16 + lm;
                    int t3 = gc >> 9, rem = gc & 511;
                    int h = rem >> 6, d = rem & 63;
                    float v = acc[mi][ni][r];
                    if (t3 == 0) v *= 0.125f;   // q pre-scale
                    C[(size_t)t3 * QSZ_ + ((size_t)(b * H_ + h) * NTOT + n) * DH_ + d] = v;
                }
            }
        }
    } else {
        float bb[4];
        #pragma unroll
        for (int ni = 0; ni < 4; ++ni)
            bb[ni] = bias[col0 + wc * 64 + ni * 16 + lm];
        #pragma unroll
        for (int mi = 0; mi < 4; ++mi) {
            #pragma unroll
            for (int r = 0; r < 4; ++r) {
                int gr = row0 + wr * 64 + mi * 16 + lq * 4 + r;
                if (gr >= MROWS) continue;
                #pragma unroll
                for (int ni = 0; ni < 4; ++ni) {
                    int gc = col0 + wc * 64 + ni * 16 + lm;
                    C[(size_t)gr * 512 + gc] = acc[mi][ni][r] + bb[ni];
                }
            }
        }
    }
}

// ---------------------------------------------------------------------------
// local attention: grid 1024 = 32 bh x 16 f x 2 halves; 128 threads; one
// thread = one q row (98 rows per block), online softmax over 197 kv rows.
// Output written bf16 into attn ws [B][NTOT][H*DH].
// ---------------------------------------------------------------------------
__global__ __launch_bounds__(128) void attn_local_kernel(
    const float* __restrict__ qws, const float* __restrict__ kws,
    const float* __restrict__ vws, u16* __restrict__ attn)
{
    __shared__ float k_s[32 * 64];
    __shared__ float v_s[32 * 64];

    const int tid  = threadIdx.x;
    const int g    = blockIdx.x;
    const int half = g & 1;
    const int f    = (g >> 1) & 15;
    const int bh   = g >> 5;
    const int r    = half * 98 + min(tid, 97);
    const int nq   = 1 + f * NP_ + r;

    float4 q4[16];
    const float4* qrow = (const float4*)(qws + ((size_t)bh * NTOT + nq) * DH_);
    #pragma unroll
    for (int i = 0; i < 16; ++i) q4[i] = qrow[i];

    float m = -INFINITY, l = 0.f;
    float4 o[16];
    #pragma unroll
    for (int i = 0; i < 16; ++i) o[i] = make_float4(0.f, 0.f, 0.f, 0.f);

    for (int jb = 0; jb < 197; jb += 32) {
        int cnt = min(32, 197 - jb);
        __syncthreads();
        for (int idx = tid; idx < cnt * 16; idx += 128) {
            int j = idx >> 4, d4 = idx & 15;
            int jj = jb + j;
            int nkv = (jj == 0) ? 0 : (1 + f * NP_ + jj - 1);
            size_t base = ((size_t)bh * NTOT + nkv) * DH_ + d4 * 4;
            *(float4*)(&k_s[j * 64 + d4 * 4]) = *(const float4*)(kws + base);
            *(float4*)(&v_s[j * 64 + d4 * 4]) = *(const float4*)(vws + base);
        }
        __syncthreads();
        for (int j = 0; j < cnt; ++j) {
            const float4* kr = (const float4*)(k_s + j * 64);
            float s0 = 0.f, s1 = 0.f, s2 = 0.f, s3 = 0.f;   // 4 chains: latency-hidden
            #pragma unroll
            for (int i = 0; i < 4; ++i) {
                float4 ka = kr[i], kb = kr[4 + i], kc = kr[8 + i], kd = kr[12 + i];
                s0 = fmaf(q4[i].x, ka.x, s0);      s0 = fmaf(q4[i].y, ka.y, s0);
                s0 = fmaf(q4[i].z, ka.z, s0);      s0 = fmaf(q4[i].w, ka.w, s0);
                s1 = fmaf(q4[4+i].x, kb.x, s1);    s1 = fmaf(q4[4+i].y, kb.y, s1);
                s1 = fmaf(q4[4+i].z, kb.z, s1);    s1 = fmaf(q4[4+i].w, kb.w, s1);
                s2 = fmaf(q4[8+i].x, kc.x, s2);    s2 = fmaf(q4[8+i].y, kc.y, s2);
                s2 = fmaf(q4[8+i].z, kc.z, s2);    s2 = fmaf(q4[8+i].w, kc.w, s2);
                s3 = fmaf(q4[12+i].x, kd.x, s3);   s3 = fmaf(q4[12+i].y, kd.y, s3);
                s3 = fmaf(q4[12+i].z, kd.z, s3);   s3 = fmaf(q4[12+i].w, kd.w, s3);
            }
            float s = (s0 + s1) + (s2 + s3);
            float mn = fmaxf(m, s);
            float p = __expf(s - mn);
            if (mn > m) {                          // rare rescale (~6x per row)
                float al = __expf(m - mn);
                l *= al;
                #pragma unroll
                for (int i = 0; i < 16; ++i) {
                    o[i].x *= al; o[i].y *= al; o[i].z *= al; o[i].w *= al;
                }
            }
            m = mn;
            l += p;
            const float4* vr = (const float4*)(v_s + j * 64);
            #pragma unroll
            for (int i = 0; i < 16; ++i) {
                float4 vv = vr[i];
                o[i].x = fmaf(p, vv.x, o[i].x);
                o[i].y = fmaf(p, vv.y, o[i].y);
                o[i].z = fmaf(p, vv.z, o[i].z);
                o[i].w = fmaf(p, vv.w, o[i].w);
            }
        }
    }
    if (tid < 98) {
        const int b = bh >> 3, h = bh & 7;
        float inv = 1.f / l;
        u16* dst = attn + ((size_t)b * NTOT + nq) * DIM_ + h * DH_;
        #pragma unroll
        for (int i = 0; i < 16; ++i) {
            float4 t = o[i];
            u16x4 p = { f2bf(t.x * inv), f2bf(t.y * inv), f2bf(t.z * inv), f2bf(t.w * inv) };
            *(u16x4*)(dst + i * 4) = p;
        }
    }
}

// ---------------------------------------------------------------------------
// cls attention, stage 1: grid (8 parts, 32 bh), 128 threads (2 waves).
// Each block: partial online softmax over its kv slice, direct global reads.
// ---------------------------------------------------------------------------
__global__ __launch_bounds__(128) void attn_cls_partial_kernel(
    const float* __restrict__ qws, const float* __restrict__ kws,
    const float* __restrict__ vws, float* __restrict__ cls_m,
    float* __restrict__ cls_l, float* __restrict__ cls_o)
{
    __shared__ float sm[2], sl[2], so[2 * 64];
    const int part = blockIdx.x, bh = blockIdx.y;
    const int lane = threadIdx.x & 63, w = threadIdx.x >> 6;
    const int start = (part * NTOT) / 8, end = ((part + 1) * NTOT) / 8;

    const float qv = qws[(size_t)bh * NTOT * DH_ + lane];   // q row 0, pre-scaled

    float m = -INFINITY, l = 0.f, o = 0.f;
    for (int j = start + w; j < end; j += 2) {
        float s = qv * kws[((size_t)bh * NTOT + j) * DH_ + lane];
        #pragma unroll
        for (int off = 32; off > 0; off >>= 1) s += __shfl_xor(s, off, 64);
        float mn = fmaxf(m, s);
        float al = __expf(m - mn);       // first iter: exp(-inf)=0
        float p  = __expf(s - mn);
        l = l * al + p;
        o = o * al + p * vws[((size_t)bh * NTOT + j) * DH_ + lane];
        m = mn;
    }
    if (lane == 0) { sm[w] = m; sl[w] = l; }
    so[w * 64 + lane] = o;
    __syncthreads();
    if (threadIdx.x < 64) {
        float M = fmaxf(sm[0], sm[1]);
        float a0 = __expf(sm[0] - M), a1 = __expf(sm[1] - M);
        float L = sl[0] * a0 + sl[1] * a1;
        float O = so[lane] * a0 + so[64 + lane] * a1;
        int pi = bh * 8 + part;
        if (lane == 0) { cls_m[pi] = M; cls_l[pi] = L; }
        cls_o[(size_t)pi * 64 + lane] = O;
    }
}

// cls stage 2: merge 8 partials per bh, write bf16 row n=0.
__global__ __launch_bounds__(64) void attn_cls_merge_kernel(
    const float* __restrict__ cls_m, const float* __restrict__ cls_l,
    const float* __restrict__ cls_o, u16* __restrict__ attn)
{
    const int bh = blockIdx.x, lane = threadIdx.x;
    float M = -INFINITY;
    #pragma unroll
    for (int p = 0; p < 8; ++p) M = fmaxf(M, cls_m[bh * 8 + p]);
    float L = 0.f, O = 0.f;
    #pragma unroll
    for (int p = 0; p < 8; ++p) {
        float al = __expf(cls_m[bh * 8 + p] - M);
        L += cls_l[bh * 8 + p] * al;
        O += cls_o[(size_t)(bh * 8 + p) * 64 + lane] * al;
    }
    const int b = bh >> 3, h = bh & 7;
    attn[(size_t)b * NTOT * DIM_ + h * DH_ + lane] = f2bf(O / L);
}

// ---------------------------------------------------------------------------
extern "C" void kernel_launch(void* const* d_in, const int* in_sizes, int n_in,
                              void* d_out, int out_size, void* d_ws, size_t ws_size,
                              hipStream_t stream) {
    const float* x    = (const float*)d_in[0];
    const float* wqkv = (const float*)d_in[1];
    const float* wout = (const float*)d_in[2];
    const float* bout = (const float*)d_in[3];

    float* ws  = (float*)d_ws;
    float* qws = ws;                    // [BH][NTOT][DH] fp32 (q pre-scaled)
    float* kws = ws + QSZ_;
    float* vws = ws + 2 * QSZ_;
    u16* xbf   = (u16*)(ws + 3 * QSZ_); // MROWS*512 bf16; REUSED as attn buffer
    u16* attn  = xbf;                   // safe: xbf consumed by qkv gemm first
    u16* wqkvT = xbf + (size_t)MROWS * 512;   // 1536 x 512 bf16
    u16* woutT = wqkvT + (size_t)1536 * 512;  // 512 x 512 bf16
    float* clsws = (float*)(woutT + (size_t)512 * 512);
    float* cls_m = clsws;               // [32*8]
    float* cls_l = clsws + 256;
    float* cls_o = clsws + 512;         // [32*8][64]
    float* outp  = (float*)d_out;

    // input conversions
    convert_x_kernel<<<6274, 256, 0, stream>>>(x, xbf);                    // 12548*512/4/256
    transpose_bf16_kernel<<<dim3(48, 16), 256, 0, stream>>>(wqkv, wqkvT, 512, 1536);
    transpose_bf16_kernel<<<dim3(16, 16), 256, 0, stream>>>(wout, woutT, 512, 512);
    // qkv = x @ W_qkv (bf16 MFMA), scatter to q/k/v
    gemm_bf16_mfma<0><<<dim3(12, 99), 256, 0, stream>>>(xbf, wqkvT, qws, nullptr);
    // attention (fp32), writes bf16 attn
    attn_local_kernel<<<1024, 128, 0, stream>>>(qws, kws, vws, attn);
    attn_cls_partial_kernel<<<dim3(8, 32), 128, 0, stream>>>(qws, kws, vws, cls_m, cls_l, cls_o);
    attn_cls_merge_kernel<<<32, 64, 0, stream>>>(cls_m, cls_l, cls_o, attn);
    // out = attn @ W_out + b_out (bf16 MFMA)
    gemm_bf16_mfma<1><<<dim3(4, 99), 256, 0, stream>>>(attn, woutT, outp, bout);
}

// Round 3
// 307.099 us; speedup vs baseline: 2.3710x; 1.5232x over previous
//
#include <hip/hip_runtime.h>
#include <math.h>

// (B, F, NP, DIM, H, DH) = (4, 16, 196, 512, 8, 64)
#define B_   4
#define F_   16
#define NP_  196
#define DIM_ 512
#define H_   8
#define DH_  64
#define NTOT 3137            // 1 + F*NP
#define BH_  32              // B*H
#define MROWS 12548          // B*NTOT
#define QSZ_ ((size_t)BH_ * NTOT * DH_)   // 6,424,576 elements per q/k/v buffer
#define KVPAD 224            // kv padded to 7 ksteps of 32
#define PSTRIDE 232          // P LDS row stride (u16): 16B-aligned, read-conflict-free

typedef unsigned short u16;
typedef __attribute__((ext_vector_type(8))) short    bf16x8;
typedef __attribute__((ext_vector_type(8))) unsigned short u16x8;
typedef __attribute__((ext_vector_type(4))) unsigned short u16x4;
typedef __attribute__((ext_vector_type(4))) float    f32x4;

__device__ __forceinline__ u16 f2bf(float f) {
    unsigned int u = __float_as_uint(f);
    unsigned int r = (u + 0x7FFFu + ((u >> 16) & 1u)) >> 16;
    return (u16)r;
}
__device__ __forceinline__ float bf2f(u16 u) {
    return __uint_as_float(((unsigned int)u) << 16);
}

// ---------------------------------------------------------------------------
// convert x (fp32, MROWS x 512) -> bf16
// ---------------------------------------------------------------------------
__global__ __launch_bounds__(256) void convert_x_kernel(
    const float* __restrict__ x, u16* __restrict__ xbf)
{
    int idx = blockIdx.x * 256 + threadIdx.x;       // one float4 per thread
    float4 v = ((const float4*)x)[idx];
    u16x4 p = { f2bf(v.x), f2bf(v.y), f2bf(v.z), f2bf(v.w) };
    *(u16x4*)(&xbf[(size_t)idx * 4]) = p;
}

// ---------------------------------------------------------------------------
// transpose + bf16-convert: src (R x C fp32) -> dst (C x R bf16)
// ---------------------------------------------------------------------------
__global__ __launch_bounds__(256) void transpose_bf16_kernel(
    const float* __restrict__ src, u16* __restrict__ dst, int R, int C)
{
    __shared__ float t[32][33];
    const int tx = threadIdx.x & 31, ty = threadIdx.x >> 5;   // ty in 0..7
    const int c0 = blockIdx.x * 32, r0 = blockIdx.y * 32;
    #pragma unroll
    for (int i = 0; i < 4; ++i) {
        int r = ty + i * 8;
        t[r][tx] = src[(size_t)(r0 + r) * C + c0 + tx];
    }
    __syncthreads();
    #pragma unroll
    for (int i = 0; i < 4; ++i) {
        int cc = ty + i * 8;
        dst[(size_t)(c0 + cc) * R + r0 + tx] = f2bf(t[tx][cc]);
    }
}

// ---------------------------------------------------------------------------
// bf16 MFMA GEMM:  C = A(MROWS x 512) * BT^T   (BT is N x 512 bf16, K-contig)
// 128x128 block tile, BK=32, 4 waves 2x2, each wave 64x64 via 4x4 mfma tiles.
// MODE 0: qkv epilogue -> bf16 q (x0.125) / k / v [bh][n][64] + per-group V^T
// MODE 1: out epilogue (+bias, fp32 row-major)
// ---------------------------------------------------------------------------
template<int MODE>
__global__ __launch_bounds__(256) void gemm_bf16_mfma(
    const u16* __restrict__ A, const u16* __restrict__ BT,
    u16* __restrict__ Cq, u16* __restrict__ Ck, u16* __restrict__ Cv,
    u16* __restrict__ CvT, float* __restrict__ Cout, const float* __restrict__ bias)
{
    __shared__ alignas(16) u16 Asm[8 * 512];   // subtile s: lane l holds A[s*16+(l&15)][k0+(l>>4)*8+j]
    __shared__ alignas(16) u16 Bsm[8 * 512];

    const int tid  = threadIdx.x;
    const int wave = tid >> 6, lane = tid & 63;
    const int wr = wave >> 1, wc = wave & 1;
    const int lm = lane & 15, lq = lane >> 4;
    const int row0 = blockIdx.y * 128;
    const int col0 = blockIdx.x * 128;

    f32x4 acc[4][4];
    #pragma unroll
    for (int i = 0; i < 4; ++i)
        #pragma unroll
        for (int j = 0; j < 4; ++j) acc[i][j] = (f32x4){0.f, 0.f, 0.f, 0.f};

    for (int k0 = 0; k0 < 512; k0 += 32) {
        #pragma unroll
        for (int i = 0; i < 2; ++i) {
            int s = wave * 2 + i;
            int arow = row0 + s * 16 + lm;
            if (arow >= MROWS) arow = MROWS - 1;
            u16x8 av = *(const u16x8*)(A + (size_t)arow * 512 + k0 + lq * 8);
            *(u16x8*)(&Asm[s * 512 + lane * 8]) = av;
            int brow = col0 + s * 16 + lm;      // row of BT = output column
            u16x8 bv = *(const u16x8*)(BT + (size_t)brow * 512 + k0 + lq * 8);
            *(u16x8*)(&Bsm[s * 512 + lane * 8]) = bv;
        }
        __syncthreads();
        bf16x8 af[4], bf[4];
        #pragma unroll
        for (int mi = 0; mi < 4; ++mi)
            af[mi] = *(const bf16x8*)(&Asm[(wr * 4 + mi) * 512 + lane * 8]);
        #pragma unroll
        for (int ni = 0; ni < 4; ++ni)
            bf[ni] = *(const bf16x8*)(&Bsm[(wc * 4 + ni) * 512 + lane * 8]);
        #pragma unroll
        for (int mi = 0; mi < 4; ++mi)
            #pragma unroll
            for (int ni = 0; ni < 4; ++ni)
                acc[mi][ni] = __builtin_amdgcn_mfma_f32_16x16x32_bf16(
                    af[mi], bf[ni], acc[mi][ni], 0, 0, 0);
        __syncthreads();
    }

    // epilogue: lane l, reg r -> row = sub16 + lq*4 + r, col = sub16 + lm
    if (MODE == 0) {
        const int t3 = col0 >> 9;          // uniform per block
        #pragma unroll
        for (int mi = 0; mi < 4; ++mi) {
            #pragma unroll
            for (int r = 0; r < 4; ++r) {
                int gr = row0 + wr * 64 + mi * 16 + lq * 4 + r;
                if (gr >= MROWS) continue;
                int b = gr / NTOT;
                int n = gr - b * NTOT;
                #pragma unroll
                for (int ni = 0; ni < 4; ++ni) {
                    int gc = col0 + wc * 64 + ni * 16 + lm;
                    int rem = gc & 511;
                    int h = rem >> 6, d = rem & 63;
                    int bh = b * H_ + h;
                    size_t tok = (size_t)bh * NTOT + n;
                    float v = acc[mi][ni][r];
                    if (t3 == 0) {
                        Cq[tok * 64 + d] = f2bf(v * 0.125f);
                    } else if (t3 == 1) {
                        Ck[tok * 64 + d] = f2bf(v);
                    } else {
                        u16 bv = f2bf(v);
                        Cv[tok * 64 + d] = bv;
                        if (n > 0) {                  // per-group V^T (cls filled later)
                            unsigned nn = (unsigned)(n - 1);
                            unsigned f = nn / 196u;
                            unsigned jj = nn - f * 196u + 1u;
                            CvT[((size_t)(bh * 16 + (int)f) * 64 + d) * KVPAD + jj] = bv;
                        }
                    }
                }
            }
        }
    } else {
        float bb[4];
        #pragma unroll
        for (int ni = 0; ni < 4; ++ni)
            bb[ni] = bias[col0 + wc * 64 + ni * 16 + lm];
        #pragma unroll
        for (int mi = 0; mi < 4; ++mi) {
            #pragma unroll
            for (int r = 0; r < 4; ++r) {
                int gr = row0 + wr * 64 + mi * 16 + lq * 4 + r;
                if (gr >= MROWS) continue;
                #pragma unroll
                for (int ni = 0; ni < 4; ++ni) {
                    int gc = col0 + wc * 64 + ni * 16 + lm;
                    Cout[(size_t)gr * 512 + gc] = acc[mi][ni][r] + bb[ni];
                }
            }
        }
    }
}

// ---------------------------------------------------------------------------
// replicate cls V row into position 0 of every group's V^T
// ---------------------------------------------------------------------------
__global__ __launch_bounds__(64) void vt_cls_fill_kernel(
    const u16* __restrict__ vb, u16* __restrict__ vT)
{
    const int bh = blockIdx.x, d = threadIdx.x;
    u16 val = vb[(size_t)bh * NTOT * 64 + d];
    #pragma unroll
    for (int f = 0; f < 16; ++f)
        vT[((size_t)(bh * 16 + f) * 64 + d) * KVPAD] = val;
}

// ---------------------------------------------------------------------------
// local attention, MFMA flash. One wave = one (bh, f, 16-q-row tile).
// 6656 wave-tasks = 1664 blocks x 4 waves. No cross-wave LDS sharing.
// S (16 x 208) held fully in registers -> single-pass softmax.
// ---------------------------------------------------------------------------
__global__ __launch_bounds__(256) void attn_mfma_kernel(
    const u16* __restrict__ qb, const u16* __restrict__ kb,
    const u16* __restrict__ vT, u16* __restrict__ attn)
{
    __shared__ alignas(16) u16 Pbuf[4 * 16 * PSTRIDE];

    const int tid  = threadIdx.x;
    const int wave = tid >> 6, lane = tid & 63;
    const int lm = lane & 15, lq = lane >> 4;
    const int task = blockIdx.x * 4 + wave;          // 0..6655
    const int mt = task % 13;
    const int gf = task / 13;
    const int f  = gf & 15;
    const int bh = gf >> 4;

    // Q A-fragments: row m = mt*16 + lm (clamped), k = kk*32 + lq*8 + j
    const int rq = min(mt * 16 + lm, 195);
    const u16* qrow = qb + ((size_t)bh * NTOT + (1 + f * NP_ + rq)) * 64;
    bf16x8 qf0 = *(const bf16x8*)(qrow + lq * 8);
    bf16x8 qf1 = *(const bf16x8*)(qrow + 32 + lq * 8);

    // S = Q K^T over 13 kv tiles of 16 (kv j = nt*16 + lm; j==0 is cls)
    f32x4 S[13];
    #pragma unroll
    for (int nt = 0; nt < 13; ++nt) {
        int rkc = min(nt * 16 + lm, 196);
        int nk = (rkc == 0) ? 0 : (1 + f * NP_ + rkc - 1);
        const u16* krow = kb + ((size_t)bh * NTOT + nk) * 64;
        bf16x8 kf0 = *(const bf16x8*)(krow + lq * 8);
        bf16x8 kf1 = *(const bf16x8*)(krow + 32 + lq * 8);
        f32x4 z = (f32x4){0.f, 0.f, 0.f, 0.f};
        z = __builtin_amdgcn_mfma_f32_16x16x32_bf16(qf0, kf0, z, 0, 0, 0);
        z = __builtin_amdgcn_mfma_f32_16x16x32_bf16(qf1, kf1, z, 0, 0, 0);
        S[nt] = z;
    }

    // mask invalid kv cols (col j = nt*16 + lm >= 197)
    #pragma unroll
    for (int nt = 0; nt < 13; ++nt)
        if (nt * 16 + lm >= 197) {
            S[nt][0] = -INFINITY; S[nt][1] = -INFINITY;
            S[nt][2] = -INFINITY; S[nt][3] = -INFINITY;
        }

    // single-pass softmax; row = lq*4 + r, cols across the 16-lane group
    float invl[4];
    #pragma unroll
    for (int r = 0; r < 4; ++r) {
        float mx = -INFINITY;
        #pragma unroll
        for (int nt = 0; nt < 13; ++nt) mx = fmaxf(mx, S[nt][r]);
        mx = fmaxf(mx, __shfl_xor(mx, 1, 64));
        mx = fmaxf(mx, __shfl_xor(mx, 2, 64));
        mx = fmaxf(mx, __shfl_xor(mx, 4, 64));
        mx = fmaxf(mx, __shfl_xor(mx, 8, 64));
        float sum = 0.f;
        #pragma unroll
        for (int nt = 0; nt < 13; ++nt) {
            float p = __expf(S[nt][r] - mx);   // exp(-inf)=0 for masked cols
            S[nt][r] = p;
            sum += p;
        }
        sum += __shfl_xor(sum, 1, 64);
        sum += __shfl_xor(sum, 2, 64);
        sum += __shfl_xor(sum, 4, 64);
        sum += __shfl_xor(sum, 8, 64);
        invl[r] = 1.f / sum;
    }

    // P -> LDS (C-layout scatter), then re-read as A-fragments
    u16* P = Pbuf + wave * 16 * PSTRIDE;
    #pragma unroll
    for (int nt = 0; nt < 13; ++nt) {
        int col = nt * 16 + lm;
        #pragma unroll
        for (int r = 0; r < 4; ++r)
            P[(lq * 4 + r) * PSTRIDE + col] = f2bf(S[nt][r]);
    }
    {   // zero cols 208..223 (A-frag reads cover up to col 224)
        u16x4 z4 = {0, 0, 0, 0};
        *(u16x4*)(P + lm * PSTRIDE + 208 + lq * 4) = z4;
    }

    // O = P * V  (B operand from per-group V^T, kv-contiguous)
    f32x4 O[4];
    #pragma unroll
    for (int nd = 0; nd < 4; ++nd) O[nd] = (f32x4){0.f, 0.f, 0.f, 0.f};
    const u16* vbase = vT + (size_t)(bh * 16 + f) * 64 * KVPAD;
    #pragma unroll
    for (int ks = 0; ks < 7; ++ks) {
        bf16x8 pf = *(const bf16x8*)(P + lm * PSTRIDE + ks * 32 + lq * 8);
        #pragma unroll
        for (int nd = 0; nd < 4; ++nd) {
            bf16x8 vf = *(const bf16x8*)(vbase + (size_t)(nd * 16 + lm) * KVPAD + ks * 32 + lq * 8);
            O[nd] = __builtin_amdgcn_mfma_f32_16x16x32_bf16(pf, vf, O[nd], 0, 0, 0);
        }
    }

    // store: row = mt*16 + lq*4 + r, col dim = nd*16 + lm
    const int b = bh >> 3, h = bh & 7;
    #pragma unroll
    for (int r = 0; r < 4; ++r) {
        int rql = mt * 16 + lq * 4 + r;
        if (rql >= 196) continue;
        int n = 1 + f * NP_ + rql;
        u16* dst = attn + ((size_t)b * NTOT + n) * 512 + h * 64;
        float s = invl[r];
        #pragma unroll
        for (int nd = 0; nd < 4; ++nd)
            dst[nd * 16 + lm] = f2bf(O[nd][r] * s);
    }
}

// ---------------------------------------------------------------------------
// cls attention, stage 1: grid (8 parts, 32 bh), 128 threads (2 waves).
// ---------------------------------------------------------------------------
__global__ __launch_bounds__(128) void attn_cls_partial_kernel(
    const u16* __restrict__ qb, const u16* __restrict__ kb,
    const u16* __restrict__ vb, float* __restrict__ cls_m,
    float* __restrict__ cls_l, float* __restrict__ cls_o)
{
    __shared__ float sm[2], sl[2], so[2 * 64];
    const int part = blockIdx.x, bh = blockIdx.y;
    const int lane = threadIdx.x & 63, w = threadIdx.x >> 6;
    const int start = (part * NTOT) / 8, end = ((part + 1) * NTOT) / 8;

    const float qv = bf2f(qb[(size_t)bh * NTOT * 64 + lane]);   // q row 0, pre-scaled

    float m = -INFINITY, l = 0.f, o = 0.f;
    for (int j = start + w; j < end; j += 2) {
        float s = qv * bf2f(kb[((size_t)bh * NTOT + j) * 64 + lane]);
        #pragma unroll
        for (int off = 32; off > 0; off >>= 1) s += __shfl_xor(s, off, 64);
        float mn = fmaxf(m, s);
        float al = __expf(m - mn);
        float p  = __expf(s - mn);
        l = l * al + p;
        o = o * al + p * bf2f(vb[((size_t)bh * NTOT + j) * 64 + lane]);
        m = mn;
    }
    if (lane == 0) { sm[w] = m; sl[w] = l; }
    so[w * 64 + lane] = o;
    __syncthreads();
    if (threadIdx.x < 64) {
        float M = fmaxf(sm[0], sm[1]);
        float a0 = __expf(sm[0] - M), a1 = __expf(sm[1] - M);
        float L = sl[0] * a0 + sl[1] * a1;
        float O = so[lane] * a0 + so[64 + lane] * a1;
        int pi = bh * 8 + part;
        if (lane == 0) { cls_m[pi] = M; cls_l[pi] = L; }
        cls_o[(size_t)pi * 64 + lane] = O;
    }
}

// cls stage 2: merge 8 partials per bh, write bf16 row n=0.
__global__ __launch_bounds__(64) void attn_cls_merge_kernel(
    const float* __restrict__ cls_m, const float* __restrict__ cls_l,
    const float* __restrict__ cls_o, u16* __restrict__ attn)
{
    const int bh = blockIdx.x, lane = threadIdx.x;
    float M = -INFINITY;
    #pragma unroll
    for (int p = 0; p < 8; ++p) M = fmaxf(M, cls_m[bh * 8 + p]);
    float L = 0.f, O = 0.f;
    #pragma unroll
    for (int p = 0; p < 8; ++p) {
        float al = __expf(cls_m[bh * 8 + p] - M);
        L += cls_l[bh * 8 + p] * al;
        O += cls_o[(size_t)(bh * 8 + p) * 64 + lane] * al;
    }
    const int b = bh >> 3, h = bh & 7;
    attn[(size_t)b * NTOT * 512 + h * 64 + lane] = f2bf(O / L);
}

// ---------------------------------------------------------------------------
extern "C" void kernel_launch(void* const* d_in, const int* in_sizes, int n_in,
                              void* d_out, int out_size, void* d_ws, size_t ws_size,
                              hipStream_t stream) {
    const float* x    = (const float*)d_in[0];
    const float* wqkv = (const float*)d_in[1];
    const float* wout = (const float*)d_in[2];
    const float* bout = (const float*)d_in[3];

    u16* p = (u16*)d_ws;
    u16* xbf   = p;                    p += (size_t)MROWS * 512;  // reused as attn
    u16* attn  = xbf;                  // safe: xbf consumed by qkv gemm before attn writes
    u16* wqkvT = p;                    p += (size_t)1536 * 512;
    u16* woutT = p;                    p += (size_t)512 * 512;
    u16* qbuf  = p;                    p += QSZ_;
    u16* kbuf  = p;                    p += QSZ_;
    u16* vbuf  = p;                    p += QSZ_;
    u16* vT    = p;                    p += (size_t)BH_ * 16 * 64 * KVPAD;
    float* clsws = (float*)p;
    float* cls_m = clsws;              // [32*8]
    float* cls_l = clsws + 256;
    float* cls_o = clsws + 512;        // [32*8][64]
    float* outp  = (float*)d_out;

    // input conversions
    convert_x_kernel<<<6274, 256, 0, stream>>>(x, xbf);
    transpose_bf16_kernel<<<dim3(48, 16), 256, 0, stream>>>(wqkv, wqkvT, 512, 1536);
    transpose_bf16_kernel<<<dim3(16, 16), 256, 0, stream>>>(wout, woutT, 512, 512);
    // qkv = x @ W_qkv (bf16 MFMA), epilogue -> bf16 q/k/v + per-group V^T
    gemm_bf16_mfma<0><<<dim3(12, 99), 256, 0, stream>>>(
        xbf, wqkvT, qbuf, kbuf, vbuf, vT, nullptr, nullptr);
    vt_cls_fill_kernel<<<32, 64, 0, stream>>>(vbuf, vT);
    // attention
    attn_mfma_kernel<<<1664, 256, 0, stream>>>(qbuf, kbuf, vT, attn);
    attn_cls_partial_kernel<<<dim3(8, 32), 128, 0, stream>>>(qbuf, kbuf, vbuf, cls_m, cls_l, cls_o);
    attn_cls_merge_kernel<<<32, 64, 0, stream>>>(cls_m, cls_l, cls_o, attn);
    // out = attn @ W_out + b_out (bf16 MFMA)
    gemm_bf16_mfma<1><<<dim3(4, 99), 256, 0, stream>>>(
        attn, woutT, nullptr, nullptr, nullptr, nullptr, outp, bout);
}

// Round 4
// 227.323 us; speedup vs baseline: 3.2031x; 1.3509x over previous
//
#include <hip/hip_runtime.h>
#include <math.h>

// (B, F, NP, DIM, H, DH) = (4, 16, 196, 512, 8, 64)
#define B_   4
#define F_   16
#define NP_  196
#define DIM_ 512
#define H_   8
#define DH_  64
#define NTOT 3137            // 1 + F*NP
#define BH_  32              // B*H
#define MROWS 12548          // B*NTOT
#define QSZ_ ((size_t)BH_ * NTOT * DH_)   // elements per q/k/v buffer
#define KVPAD 224            // kv padded to 7 ksteps of 32
#define PSTRIDE 232          // P LDS row stride (u16): 16B-aligned, read-conflict-free
#define NCHUNK 13            // cls kv chunks of 256

typedef unsigned short u16;
typedef __attribute__((ext_vector_type(8))) short    bf16x8;
typedef __attribute__((ext_vector_type(8))) unsigned short u16x8;
typedef __attribute__((ext_vector_type(4))) unsigned short u16x4;
typedef __attribute__((ext_vector_type(4))) float    f32x4;

__device__ __forceinline__ u16 f2bf(float f) {
    unsigned int u = __float_as_uint(f);
    unsigned int r = (u + 0x7FFFu + ((u >> 16) & 1u)) >> 16;
    return (u16)r;
}
__device__ __forceinline__ float bf2f(u16 u) {
    return __uint_as_float(((unsigned int)u) << 16);
}

// async global->LDS, 16B per lane. LDS dest must be wave-uniform base + lane*16.
__device__ __forceinline__ void gl2lds16(const u16* g, u16* l) {
    __builtin_amdgcn_global_load_lds(
        (const __attribute__((address_space(1))) unsigned int*)(g),
        (__attribute__((address_space(3))) unsigned int*)(l),
        16, 0, 0);
}

// ---------------------------------------------------------------------------
// convert x (fp32, MROWS x 512) -> bf16
// ---------------------------------------------------------------------------
__global__ __launch_bounds__(256) void convert_x_kernel(
    const float* __restrict__ x, u16* __restrict__ xbf)
{
    int idx = blockIdx.x * 256 + threadIdx.x;       // one float4 per thread
    float4 v = ((const float4*)x)[idx];
    u16x4 p = { f2bf(v.x), f2bf(v.y), f2bf(v.z), f2bf(v.w) };
    *(u16x4*)(&xbf[(size_t)idx * 4]) = p;
}

// ---------------------------------------------------------------------------
// transpose + bf16-convert: src (R x C fp32) -> dst (C x R bf16)
// ---------------------------------------------------------------------------
__global__ __launch_bounds__(256) void transpose_bf16_kernel(
    const float* __restrict__ src, u16* __restrict__ dst, int R, int C)
{
    __shared__ float t[32][33];
    const int tx = threadIdx.x & 31, ty = threadIdx.x >> 5;   // ty in 0..7
    const int c0 = blockIdx.x * 32, r0 = blockIdx.y * 32;
    #pragma unroll
    for (int i = 0; i < 4; ++i) {
        int r = ty + i * 8;
        t[r][tx] = src[(size_t)(r0 + r) * C + c0 + tx];
    }
    __syncthreads();
    #pragma unroll
    for (int i = 0; i < 4; ++i) {
        int cc = ty + i * 8;
        dst[(size_t)(c0 + cc) * R + r0 + tx] = f2bf(t[tx][cc]);
    }
}

// ---------------------------------------------------------------------------
// bf16 MFMA GEMM:  C = A(MROWS x 512) * BT^T   (BT is N x 512 bf16, K-contig)
// 128x128 block tile, BK=32, 4 waves 2x2, each wave 64x64 via 4x4 mfma tiles.
// Staging via async global_load_lds width=16 (wave-uniform base + lane*16).
// MODE 0: qkv epilogue -> bf16 q (x0.125) / k / v [bh][n][64] + per-group V^T
// MODE 1: out epilogue (+bias, fp32 row-major)
// ---------------------------------------------------------------------------
template<int MODE>
__global__ __launch_bounds__(256) void gemm_bf16_mfma(
    const u16* __restrict__ A, const u16* __restrict__ BT,
    u16* __restrict__ Cq, u16* __restrict__ Ck, u16* __restrict__ Cv,
    u16* __restrict__ CvT, float* __restrict__ Cout, const float* __restrict__ bias)
{
    __shared__ alignas(16) u16 Asm[8 * 512];   // subtile s: lane l holds A[s*16+(l&15)][k0+(l>>4)*8+j]
    __shared__ alignas(16) u16 Bsm[8 * 512];

    const int tid  = threadIdx.x;
    const int wave = tid >> 6, lane = tid & 63;
    const int wr = wave >> 1, wc = wave & 1;
    const int lm = lane & 15, lq = lane >> 4;
    const int row0 = blockIdx.y * 128;
    const int col0 = blockIdx.x * 128;

    f32x4 acc[4][4];
    #pragma unroll
    for (int i = 0; i < 4; ++i)
        #pragma unroll
        for (int j = 0; j < 4; ++j) acc[i][j] = (f32x4){0.f, 0.f, 0.f, 0.f};

    for (int k0 = 0; k0 < 512; k0 += 32) {
        #pragma unroll
        for (int i = 0; i < 2; ++i) {
            int s = wave * 2 + i;
            int arow = row0 + s * 16 + lm;
            if (arow >= MROWS) arow = MROWS - 1;
            gl2lds16(A + (size_t)arow * 512 + k0 + lq * 8, &Asm[s * 512 + lane * 8]);
            int brow = col0 + s * 16 + lm;      // row of BT = output column
            gl2lds16(BT + (size_t)brow * 512 + k0 + lq * 8, &Bsm[s * 512 + lane * 8]);
        }
        __syncthreads();                        // compiler drains vmcnt before barrier
        bf16x8 af[4], bf[4];
        #pragma unroll
        for (int mi = 0; mi < 4; ++mi)
            af[mi] = *(const bf16x8*)(&Asm[(wr * 4 + mi) * 512 + lane * 8]);
        #pragma unroll
        for (int ni = 0; ni < 4; ++ni)
            bf[ni] = *(const bf16x8*)(&Bsm[(wc * 4 + ni) * 512 + lane * 8]);
        #pragma unroll
        for (int mi = 0; mi < 4; ++mi)
            #pragma unroll
            for (int ni = 0; ni < 4; ++ni)
                acc[mi][ni] = __builtin_amdgcn_mfma_f32_16x16x32_bf16(
                    af[mi], bf[ni], acc[mi][ni], 0, 0, 0);
        __syncthreads();
    }

    // epilogue: lane l, reg r -> row = sub16 + lq*4 + r, col = sub16 + lm
    if (MODE == 0) {
        const int t3 = col0 >> 9;          // uniform per block
        #pragma unroll
        for (int mi = 0; mi < 4; ++mi) {
            #pragma unroll
            for (int r = 0; r < 4; ++r) {
                int gr = row0 + wr * 64 + mi * 16 + lq * 4 + r;
                if (gr >= MROWS) continue;
                int b = gr / NTOT;
                int n = gr - b * NTOT;
                #pragma unroll
                for (int ni = 0; ni < 4; ++ni) {
                    int gc = col0 + wc * 64 + ni * 16 + lm;
                    int rem = gc & 511;
                    int h = rem >> 6, d = rem & 63;
                    int bh = b * H_ + h;
                    size_t tok = (size_t)bh * NTOT + n;
                    float v = acc[mi][ni][r];
                    if (t3 == 0) {
                        Cq[tok * 64 + d] = f2bf(v * 0.125f);
                    } else if (t3 == 1) {
                        Ck[tok * 64 + d] = f2bf(v);
                    } else {
                        u16 bv = f2bf(v);
                        Cv[tok * 64 + d] = bv;
                        if (n > 0) {                  // per-group V^T (cls filled later)
                            unsigned nn = (unsigned)(n - 1);
                            unsigned f = nn / 196u;
                            unsigned jj = nn - f * 196u + 1u;
                            CvT[((size_t)(bh * 16 + (int)f) * 64 + d) * KVPAD + jj] = bv;
                        }
                    }
                }
            }
        }
    } else {
        float bb[4];
        #pragma unroll
        for (int ni = 0; ni < 4; ++ni)
            bb[ni] = bias[col0 + wc * 64 + ni * 16 + lm];
        #pragma unroll
        for (int mi = 0; mi < 4; ++mi) {
            #pragma unroll
            for (int r = 0; r < 4; ++r) {
                int gr = row0 + wr * 64 + mi * 16 + lq * 4 + r;
                if (gr >= MROWS) continue;
                #pragma unroll
                for (int ni = 0; ni < 4; ++ni) {
                    int gc = col0 + wc * 64 + ni * 16 + lm;
                    Cout[(size_t)gr * 512 + gc] = acc[mi][ni][r] + bb[ni];
                }
            }
        }
    }
}

// ---------------------------------------------------------------------------
// replicate cls V row into position 0 of every group's V^T
// ---------------------------------------------------------------------------
__global__ __launch_bounds__(64) void vt_cls_fill_kernel(
    const u16* __restrict__ vb, u16* __restrict__ vT)
{
    const int bh = blockIdx.x, d = threadIdx.x;
    u16 val = vb[(size_t)bh * NTOT * 64 + d];
    #pragma unroll
    for (int f = 0; f < 16; ++f)
        vT[((size_t)(bh * 16 + f) * 64 + d) * KVPAD] = val;
}

// ---------------------------------------------------------------------------
// local attention, MFMA flash. One wave = one (bh, f, 16-q-row tile).
// ---------------------------------------------------------------------------
__global__ __launch_bounds__(256) void attn_mfma_kernel(
    const u16* __restrict__ qb, const u16* __restrict__ kb,
    const u16* __restrict__ vT, u16* __restrict__ attn)
{
    __shared__ alignas(16) u16 Pbuf[4 * 16 * PSTRIDE];

    const int tid  = threadIdx.x;
    const int wave = tid >> 6, lane = tid & 63;
    const int lm = lane & 15, lq = lane >> 4;
    const int task = blockIdx.x * 4 + wave;          // 0..6655
    const int mt = task % 13;
    const int gf = task / 13;
    const int f  = gf & 15;
    const int bh = gf >> 4;

    const int rq = min(mt * 16 + lm, 195);
    const u16* qrow = qb + ((size_t)bh * NTOT + (1 + f * NP_ + rq)) * 64;
    bf16x8 qf0 = *(const bf16x8*)(qrow + lq * 8);
    bf16x8 qf1 = *(const bf16x8*)(qrow + 32 + lq * 8);

    // S = Q K^T over 13 kv tiles of 16 (kv j = nt*16 + lm; j==0 is cls)
    f32x4 S[13];
    #pragma unroll
    for (int nt = 0; nt < 13; ++nt) {
        int rkc = min(nt * 16 + lm, 196);
        int nk = (rkc == 0) ? 0 : (1 + f * NP_ + rkc - 1);
        const u16* krow = kb + ((size_t)bh * NTOT + nk) * 64;
        bf16x8 kf0 = *(const bf16x8*)(krow + lq * 8);
        bf16x8 kf1 = *(const bf16x8*)(krow + 32 + lq * 8);
        f32x4 z = (f32x4){0.f, 0.f, 0.f, 0.f};
        z = __builtin_amdgcn_mfma_f32_16x16x32_bf16(qf0, kf0, z, 0, 0, 0);
        z = __builtin_amdgcn_mfma_f32_16x16x32_bf16(qf1, kf1, z, 0, 0, 0);
        S[nt] = z;
    }

    #pragma unroll
    for (int nt = 0; nt < 13; ++nt)
        if (nt * 16 + lm >= 197) {
            S[nt][0] = -INFINITY; S[nt][1] = -INFINITY;
            S[nt][2] = -INFINITY; S[nt][3] = -INFINITY;
        }

    // single-pass softmax; row = lq*4 + r, cols across the 16-lane group
    float invl[4];
    #pragma unroll
    for (int r = 0; r < 4; ++r) {
        float mx = -INFINITY;
        #pragma unroll
        for (int nt = 0; nt < 13; ++nt) mx = fmaxf(mx, S[nt][r]);
        mx = fmaxf(mx, __shfl_xor(mx, 1, 64));
        mx = fmaxf(mx, __shfl_xor(mx, 2, 64));
        mx = fmaxf(mx, __shfl_xor(mx, 4, 64));
        mx = fmaxf(mx, __shfl_xor(mx, 8, 64));
        float sum = 0.f;
        #pragma unroll
        for (int nt = 0; nt < 13; ++nt) {
            float p = __expf(S[nt][r] - mx);   // exp(-inf)=0 for masked cols
            S[nt][r] = p;
            sum += p;
        }
        sum += __shfl_xor(sum, 1, 64);
        sum += __shfl_xor(sum, 2, 64);
        sum += __shfl_xor(sum, 4, 64);
        sum += __shfl_xor(sum, 8, 64);
        invl[r] = 1.f / sum;
    }

    // P -> LDS (C-layout scatter), then re-read as A-fragments
    u16* P = Pbuf + wave * 16 * PSTRIDE;
    #pragma unroll
    for (int nt = 0; nt < 13; ++nt) {
        int col = nt * 16 + lm;
        #pragma unroll
        for (int r = 0; r < 4; ++r)
            P[(lq * 4 + r) * PSTRIDE + col] = f2bf(S[nt][r]);
    }
    {   // zero cols 208..223 (A-frag reads cover up to col 224)
        u16x4 z4 = {0, 0, 0, 0};
        *(u16x4*)(P + lm * PSTRIDE + 208 + lq * 4) = z4;
    }

    // O = P * V  (B operand from per-group V^T, kv-contiguous)
    f32x4 O[4];
    #pragma unroll
    for (int nd = 0; nd < 4; ++nd) O[nd] = (f32x4){0.f, 0.f, 0.f, 0.f};
    const u16* vbase = vT + (size_t)(bh * 16 + f) * 64 * KVPAD;
    #pragma unroll
    for (int ks = 0; ks < 7; ++ks) {
        bf16x8 pf = *(const bf16x8*)(P + lm * PSTRIDE + ks * 32 + lq * 8);
        #pragma unroll
        for (int nd = 0; nd < 4; ++nd) {
            bf16x8 vf = *(const bf16x8*)(vbase + (size_t)(nd * 16 + lm) * KVPAD + ks * 32 + lq * 8);
            O[nd] = __builtin_amdgcn_mfma_f32_16x16x32_bf16(pf, vf, O[nd], 0, 0, 0);
        }
    }

    const int b = bh >> 3, h = bh & 7;
    #pragma unroll
    for (int r = 0; r < 4; ++r) {
        int rql = mt * 16 + lq * 4 + r;
        if (rql >= 196) continue;
        int n = 1 + f * NP_ + rql;
        u16* dst = attn + ((size_t)b * NTOT + n) * 512 + h * 64;
        float s = invl[r];
        #pragma unroll
        for (int nd = 0; nd < 4; ++nd)
            dst[nd * 16 + lm] = f2bf(O[nd][r] * s);
    }
}

// ---------------------------------------------------------------------------
// cls attention, stage 1 (v2): grid (13 chunks, 32 bh), 256 threads.
// Phase A: thread = kv row; dot via 16B gather loads, 4 indep FMA chains.
// Phase B: thread = (quarter, d); P broadcast from LDS, V coalesced.
// Writes partial (m, l, o[64]) per (bh, chunk).
// ---------------------------------------------------------------------------
__global__ __launch_bounds__(256) void attn_cls_partial_kernel(
    const u16* __restrict__ qb, const u16* __restrict__ kb,
    const u16* __restrict__ vb, float* __restrict__ cls_m,
    float* __restrict__ cls_l, float* __restrict__ cls_o)
{
    __shared__ float qs[64];
    __shared__ float redm[4], redl[4];
    __shared__ float ps[256];
    __shared__ float so[4][64];

    const int c = blockIdx.x, bh = blockIdx.y;
    const int t = threadIdx.x;
    const int lane = t & 63, w = t >> 6;

    if (t < 64) qs[t] = bf2f(qb[(size_t)bh * NTOT * 64 + t]);   // q row 0, pre-scaled
    __syncthreads();

    // phase A: score for kv row j = c*256 + t
    const int j = c * 256 + t;
    const bool valid = (j < NTOT);
    const int jc = valid ? j : (NTOT - 1);
    const u16* krow = kb + ((size_t)bh * NTOT + jc) * 64;
    float s0 = 0.f, s1 = 0.f, s2 = 0.f, s3 = 0.f;
    #pragma unroll
    for (int i = 0; i < 8; ++i) {
        u16x8 k8 = *(const u16x8*)(krow + i * 8);
        const float* qp = qs + i * 8;
        s0 = fmaf(qp[0], bf2f(k8[0]), s0);
        s1 = fmaf(qp[1], bf2f(k8[1]), s1);
        s2 = fmaf(qp[2], bf2f(k8[2]), s2);
        s3 = fmaf(qp[3], bf2f(k8[3]), s3);
        s0 = fmaf(qp[4], bf2f(k8[4]), s0);
        s1 = fmaf(qp[5], bf2f(k8[5]), s1);
        s2 = fmaf(qp[6], bf2f(k8[6]), s2);
        s3 = fmaf(qp[7], bf2f(k8[7]), s3);
    }
    float s = (s0 + s1) + (s2 + s3);
    if (!valid) s = -INFINITY;

    // block max
    float mx = s;
    #pragma unroll
    for (int off = 1; off < 64; off <<= 1) mx = fmaxf(mx, __shfl_xor(mx, off, 64));
    if (lane == 0) redm[w] = mx;
    __syncthreads();
    mx = fmaxf(fmaxf(redm[0], redm[1]), fmaxf(redm[2], redm[3]));

    float pv = __expf(s - mx);                 // -inf -> 0
    float l = pv;
    #pragma unroll
    for (int off = 1; off < 64; off <<= 1) l += __shfl_xor(l, off, 64);
    if (lane == 0) redl[w] = l;
    ps[t] = pv;
    __syncthreads();
    l = redl[0] + redl[1] + redl[2] + redl[3];

    // phase B: o_d partial over this chunk's quarter
    const int d = lane, part = w;
    float o = 0.f;
    #pragma unroll 8
    for (int i = 0; i < 64; ++i) {
        int jj = c * 256 + part * 64 + i;
        int jjc = (jj < NTOT) ? jj : (NTOT - 1);
        o = fmaf(ps[part * 64 + i], bf2f(vb[((size_t)bh * NTOT + jjc) * 64 + d]), o);
    }
    so[part][d] = o;
    __syncthreads();
    if (t < 64) {
        float O = so[0][t] + so[1][t] + so[2][t] + so[3][t];
        int pi = bh * NCHUNK + c;
        cls_o[(size_t)pi * 64 + t] = O;
        if (t == 0) { cls_m[pi] = mx; cls_l[pi] = l; }
    }
}

// cls stage 2: merge 13 partials per bh, write bf16 row n=0.
__global__ __launch_bounds__(64) void attn_cls_merge_kernel(
    const float* __restrict__ cls_m, const float* __restrict__ cls_l,
    const float* __restrict__ cls_o, u16* __restrict__ attn)
{
    const int bh = blockIdx.x, lane = threadIdx.x;
    float M = -INFINITY;
    #pragma unroll
    for (int p = 0; p < NCHUNK; ++p) M = fmaxf(M, cls_m[bh * NCHUNK + p]);
    float L = 0.f, O = 0.f;
    #pragma unroll
    for (int p = 0; p < NCHUNK; ++p) {
        float al = __expf(cls_m[bh * NCHUNK + p] - M);
        L += cls_l[bh * NCHUNK + p] * al;
        O += cls_o[(size_t)(bh * NCHUNK + p) * 64 + lane] * al;
    }
    const int b = bh >> 3, h = bh & 7;
    attn[(size_t)b * NTOT * 512 + h * 64 + lane] = f2bf(O / L);
}

// ---------------------------------------------------------------------------
extern "C" void kernel_launch(void* const* d_in, const int* in_sizes, int n_in,
                              void* d_out, int out_size, void* d_ws, size_t ws_size,
                              hipStream_t stream) {
    const float* x    = (const float*)d_in[0];
    const float* wqkv = (const float*)d_in[1];
    const float* wout = (const float*)d_in[2];
    const float* bout = (const float*)d_in[3];

    u16* p = (u16*)d_ws;
    u16* xbf   = p;                    p += (size_t)MROWS * 512;  // reused as attn
    u16* attn  = xbf;                  // safe: xbf consumed by qkv gemm before attn writes
    u16* wqkvT = p;                    p += (size_t)1536 * 512;
    u16* woutT = p;                    p += (size_t)512 * 512;
    u16* qbuf  = p;                    p += QSZ_;
    u16* kbuf  = p;                    p += QSZ_;
    u16* vbuf  = p;                    p += QSZ_;
    u16* vT    = p;                    p += (size_t)BH_ * 16 * 64 * KVPAD;
    float* clsws = (float*)p;
    float* cls_m = clsws;                       // [32*13]
    float* cls_l = clsws + BH_ * NCHUNK;        // [32*13]
    float* cls_o = clsws + 2 * BH_ * NCHUNK;    // [32*13][64]
    float* outp  = (float*)d_out;

    // input conversions
    convert_x_kernel<<<6274, 256, 0, stream>>>(x, xbf);
    transpose_bf16_kernel<<<dim3(48, 16), 256, 0, stream>>>(wqkv, wqkvT, 512, 1536);
    transpose_bf16_kernel<<<dim3(16, 16), 256, 0, stream>>>(wout, woutT, 512, 512);
    // qkv = x @ W_qkv (bf16 MFMA), epilogue -> bf16 q/k/v + per-group V^T
    gemm_bf16_mfma<0><<<dim3(12, 99), 256, 0, stream>>>(
        xbf, wqkvT, qbuf, kbuf, vbuf, vT, nullptr, nullptr);
    vt_cls_fill_kernel<<<32, 64, 0, stream>>>(vbuf, vT);
    // attention
    attn_mfma_kernel<<<1664, 256, 0, stream>>>(qbuf, kbuf, vT, attn);
    attn_cls_partial_kernel<<<dim3(NCHUNK, 32), 256, 0, stream>>>(
        qbuf, kbuf, vbuf, cls_m, cls_l, cls_o);
    attn_cls_merge_kernel<<<32, 64, 0, stream>>>(cls_m, cls_l, cls_o, attn);
    // out = attn @ W_out + b_out (bf16 MFMA)
    gemm_bf16_mfma<1><<<dim3(4, 99), 256, 0, stream>>>(
        attn, woutT, nullptr, nullptr, nullptr, nullptr, outp, bout);
}